// Round 1
// baseline (586.637 us; speedup 1.0000x reference)
//
#include <hip/hip_runtime.h>

// Convection / per-channel bilinear translation of [B,C,H,W] f32 grid.
// B=8, C=128, H=256, W=256 — all powers of two, index math is shifts/masks.
constexpr int Bn = 8, Cn = 128, Hn = 256, Wn = 256;

__global__ __launch_bounds__(256) void convection_kernel(
    const float* __restrict__ in, const float* __restrict__ c, float* __restrict__ out)
{
    const long long n4 = (long long)Bn * Cn * Hn * Wn / 4;   // float4 count
    const long long stride = (long long)gridDim.x * blockDim.x;
    for (long long i4 = (long long)blockIdx.x * blockDim.x + threadIdx.x; i4 < n4; i4 += stride) {
        const long long idx = i4 << 2;                        // element index
        const int w  = (int)(idx & (Wn - 1));                 // 0..252, step 4
        const int h  = (int)((idx >> 8) & (Hn - 1));
        const int ch = (int)((idx >> 16) & (Cn - 1));
        const int b  = (int)(idx >> 23);

        // wave-uniform channel params (L1-hot broadcast load)
        const float cy = c[2 * ch];
        const float cx = c[2 * ch + 1];

        // ---- vertical: replicate reference f32 rounding exactly ----
        const float posy = (float)h - cy;
        const float y0f  = floorf(posy);
        const float wy   = posy - y0f;
        const int   y0   = (int)y0f;
        const int   y1   = y0 + 1;
        const bool  vy0  = (unsigned)y0 < (unsigned)Hn;
        const bool  vy1  = (unsigned)y1 < (unsigned)Hn;
        // fold zero-padding validity into the weights (exact 0/1 multiplies)
        const float fy0  = vy0 ? (1.0f - wy) : 0.0f;
        const float fy1  = vy1 ? wy          : 0.0f;

        const float* plane = in + (((long long)b * Cn + ch) << 16);
        const float* row0  = plane + ((long long)(vy0 ? y0 : 0) << 8);  // clamped: loads stay in-bounds
        const float* row1  = plane + ((long long)(vy1 ? y1 : 0) << 8);

        float4 r;
        float* rp = reinterpret_cast<float*>(&r);
        #pragma unroll
        for (int j = 0; j < 4; ++j) {
            // ---- horizontal: per-column exact f32 replication ----
            const float posx = (float)(w + j) - cx;
            const float x0f  = floorf(posx);
            const float wx   = posx - x0f;
            const int   x0   = (int)x0f;
            const int   x1   = x0 + 1;
            const bool  vx0  = (unsigned)x0 < (unsigned)Wn;
            const bool  vx1  = (unsigned)x1 < (unsigned)Wn;
            const float fx0  = vx0 ? (1.0f - wx) : 0.0f;
            const float fx1  = vx1 ? wx          : 0.0f;
            const int   x0c  = vx0 ? x0 : 0;
            const int   x1c  = vx1 ? x1 : 0;

            const float colA = fy0 * row0[x0c] + fy1 * row1[x0c];
            const float colB = fy0 * row0[x1c] + fy1 * row1[x1c];
            rp[j] = fx0 * colA + fx1 * colB;
        }
        *reinterpret_cast<float4*>(out + idx) = r;
    }
}

extern "C" void kernel_launch(void* const* d_in, const int* in_sizes, int n_in,
                              void* d_out, int out_size, void* d_ws, size_t ws_size,
                              hipStream_t stream) {
    const float* in = (const float*)d_in[0];
    const float* c  = (const float*)d_in[1];
    float* out      = (float*)d_out;

    dim3 block(256);
    dim3 grid(2048);   // memory-bound: cap grid, grid-stride the rest (G11)
    hipLaunchKernelGGL(convection_kernel, grid, block, 0, stream, in, c, out);
}

// Round 3
// 436.286 us; speedup vs baseline: 1.3446x; 1.3446x over previous
//
#include <hip/hip_runtime.h>

// Per-channel bilinear translation of [B,C,H,W] f32 grid.
// Key structural fact: for fixed channel, the horizontal shift is a constant
// integer offset D = floor(-cx) plus per-column fractional weights. One wave
// processes one full row (256 floats = 64 lanes x float4): coalesced loads,
// vertical lerp in-register, horizontal shift via cross-lane shuffle.
constexpr int Bn = 8, Cn = 128, Hn = 256, Wn = 256;
constexpr int NROWS = Bn * Cn * Hn;   // 262144 rows

__global__ __launch_bounds__(256) void convection_kernel(
    const float* __restrict__ in, const float* __restrict__ cvec, float* __restrict__ out)
{
    const int lane = threadIdx.x & 63;
    const int wavesPerBlock = blockDim.x >> 6;
    int wave = (int)blockIdx.x * wavesPerBlock + (threadIdx.x >> 6);
    wave = __builtin_amdgcn_readfirstlane(wave);          // whole scalar chain stays SGPR
    const int nWaves = (int)gridDim.x * wavesPerBlock;

    for (int row = wave; row < NROWS; row += nWaves) {
        const int h     = row & (Hn - 1);
        const int plIdx = row >> 8;                        // b*C + ch
        const int ch    = plIdx & (Cn - 1);

        const float cy = cvec[2 * ch];                     // uniform -> s_load
        const float cx = cvec[2 * ch + 1];

        // ---- vertical lerp: exact per-element f32 replication of reference ----
        const float posy = (float)h - cy;
        const float y0f  = floorf(posy);
        const float wy   = posy - y0f;
        const int   y0   = (int)y0f;
        const int   y1   = y0 + 1;
        const bool  vy0  = (unsigned)y0 < (unsigned)Hn;
        const bool  vy1  = (unsigned)y1 < (unsigned)Hn;
        const float fy0  = vy0 ? (1.0f - wy) : 0.0f;       // zero-pad folded into weights
        const float fy1  = vy1 ? wy : 0.0f;

        const float* plane = in + ((long long)plIdx << 16);
        const float* p0 = plane + ((vy0 ? y0 : 0) << 8);   // clamped: loads in-bounds
        const float* p1 = plane + ((vy1 ? y1 : 0) << 8);

        const float4 av = *(const float4*)(p0 + 4 * lane); // coalesced 1KB/instr
        const float4 bv = *(const float4*)(p1 + 4 * lane);

        float t0 = fy0 * av.x + fy1 * bv.x;
        float t1 = fy0 * av.y + fy1 * bv.y;
        float t2 = fy0 * av.z + fy1 * bv.z;
        float t3 = fy0 * av.w + fy1 * bv.w;

        // ---- horizontal: uniform integer shift D, per-column frac weights ----
        // Rounding drift vs reference's per-element floor is absorbed by wx
        // falling slightly outside [0,1] (ulp-level value difference) and by
        // validity masks on the true tap indices.
        int D = (int)floorf(-cx);
        if (D < -512) D = -512;                            // pathology guard: all-invalid -> 0
        if (D >  512) D =  512;
        D = __builtin_amdgcn_readfirstlane(D);
        const int s = D >> 2;                              // arithmetic shift = floor div
        const int r = D & 3;

        int srcA = lane + s;     srcA = srcA < 0 ? 0 : (srcA > 63 ? 63 : srcA);
        int srcB = lane + s + 1; srcB = srcB < 0 ? 0 : (srcB > 63 ? 63 : srcB);
        // clamped-shuffle garbage is always weight-masked (true idx OOB there)

        const float A0 = __shfl(t0, srcA), A1 = __shfl(t1, srcA),
                    A2 = __shfl(t2, srcA), A3 = __shfl(t3, srcA);
        const float B0 = __shfl(t0, srcB), B1 = __shfl(t1, srcB),
                    B2 = __shfl(t2, srcB), B3 = __shfl(t3, srcB);

        // 5-element window tmp[4*lane+D .. +4]; r is wave-uniform -> scalar branch
        float win0, win1, win2, win3, win4;
        switch (r) {
            case 0:  win0 = A0; win1 = A1; win2 = A2; win3 = A3; win4 = B0; break;
            case 1:  win0 = A1; win1 = A2; win2 = A3; win3 = B0; win4 = B1; break;
            case 2:  win0 = A2; win1 = A3; win2 = B0; win3 = B1; win4 = B2; break;
            default: win0 = A3; win1 = B0; win2 = B1; win3 = B2; win4 = B3; break;
        }
        const float wins[5] = {win0, win1, win2, win3, win4};  // unrolled const idx -> regs

        const int   e0base = 4 * lane + D;
        const float wbase  = (float)(4 * lane);
        float res[4];
        #pragma unroll
        for (int j = 0; j < 4; ++j) {
            const int   e0   = e0base + j;
            const float posx = (wbase + (float)j) - cx;    // reference's exact f32 pos_x
            const float wx   = posx - (float)e0;
            const float fx0  = ((unsigned)e0       < (unsigned)Wn) ? (1.0f - wx) : 0.0f;
            const float fx1  = ((unsigned)(e0 + 1) < (unsigned)Wn) ? wx          : 0.0f;
            res[j] = fx0 * wins[j] + fx1 * wins[j + 1];
        }
        const float4 o = {res[0], res[1], res[2], res[3]};
        *(float4*)(out + ((long long)row << 8) + 4 * lane) = o;   // coalesced 1KB/instr
    }
}

extern "C" void kernel_launch(void* const* d_in, const int* in_sizes, int n_in,
                              void* d_out, int out_size, void* d_ws, size_t ws_size,
                              hipStream_t stream) {
    const float* in = (const float*)d_in[0];
    const float* c  = (const float*)d_in[1];
    float* out      = (float*)d_out;

    dim3 block(256);
    dim3 grid(2048);   // 8192 waves = 32 waves/CU -> full occupancy, 32 rows/wave
    hipLaunchKernelGGL(convection_kernel, grid, block, 0, stream, in, c, out);
}